// Round 2
// baseline (165.905 us; speedup 1.0000x reference)
//
#include <hip/hip_runtime.h>
#include <math.h>

#define BATCH  256
#define NQ     1000
#define NC     80
#define NDET   300
#define THREADS 1024
#define NWAVE  (THREADS / 64)
#define SCORE_TH 0.05f

__global__ __launch_bounds__(THREADS) void rtdetr_post_kernel(
    const float* __restrict__ logits,   // [B, Q, C]
    const float* __restrict__ boxes,    // [B, Q, 4]
    const float* __restrict__ sizes,    // [B, 2] (h, w)
    float* __restrict__ out)            // scores[B*K] | labels[B*K] | boxes[B*K*4]
{
    // compacted valid entries: (score, original index as int bits)
    __shared__ __align__(16) float2 s_cs[NQ];
    __shared__ unsigned long long s_wmask[NWAVE];

    const int b    = blockIdx.x;
    const int t    = threadIdx.x;
    const int lane = t & 63;
    const int wid  = t >> 6;

    // ---------- Phase 1: argmax over raw logits (sigmoid is monotone), ----------
    // ---------- then ONE sigmoid for the winning class.                 ----------
    float ms   = -1.0f;   // masked score (exactly -1.0 when invalid, like reference)
    int   lbl  = 0;
    bool  valid = false;

    if (t < NQ) {
        const float4* p = (const float4*)(logits + (size_t)b * NQ * NC + (size_t)t * NC);
        float best = -1e30f;
        int   bestc = 0;
        #pragma unroll
        for (int i = 0; i < NC / 4; ++i) {
            float4 v = p[i];
            // strict > keeps FIRST index among equal logits (argmax semantics)
            if (v.x > best) { best = v.x; bestc = 4 * i + 0; }
            if (v.y > best) { best = v.y; bestc = 4 * i + 1; }
            if (v.z > best) { best = v.z; bestc = 4 * i + 2; }
            if (v.w > best) { best = v.w; bestc = 4 * i + 3; }
        }
        float sc = 1.0f / (1.0f + expf(-best));   // same fp32 expression as reference
        valid = sc > SCORE_TH;
        ms    = valid ? sc : -1.0f;
        lbl   = bestc;
    }

    // ---------- Ballot prefix: count of valid entries, per-thread prefixes ----------
    unsigned long long m = __ballot(valid);
    if (lane == 0) s_wmask[wid] = m;
    __syncthreads();

    int beforeWave = 0, V = 0;
    #pragma unroll
    for (int w = 0; w < NWAVE; ++w) {
        int c = __popcll(s_wmask[w]);
        if (w < wid) beforeWave += c;
        V += c;
    }
    const int pv = beforeWave + __popcll(m & ((1ull << lane) - 1ull)); // #valid with idx < t

    // ---------- Compact valid (score, idx) into LDS ----------
    if (valid) s_cs[pv] = make_float2(ms, __int_as_float(t));
    __syncthreads();

    // ---------- Phase 2: exact stable rank ----------
    // valid:   rank among valid by (score desc, idx asc)  -> 0..V-1
    // invalid: all are exactly -1.0; stable top_k orders them by idx -> V + #invalid before t
    int rank;
    if (valid) {
        rank = 0;
        for (int j = 0; j < V; ++j) {
            float2 c = s_cs[j];            // broadcast read, conflict-free
            int ci = __float_as_int(c.y);
            rank += (c.x > ms) || (c.x == ms && ci < t);
        }
    } else {
        rank = V + (t - pv);               // for t >= NQ this is >= NQ, never writes
    }

    // ---------- Write: ranks are a bijection on [0,1000) -> exactly 300 writers ----------
    if (rank < NDET) {
        float* out_scores = out;
        float* out_labels = out + (size_t)BATCH * NDET;
        float* out_boxes  = out + (size_t)2 * BATCH * NDET;
        const int o = b * NDET + rank;

        if (valid) {
            out_scores[o] = ms;
            out_labels[o] = (float)lbl;
            float4 bx = ((const float4*)boxes)[b * NQ + t];   // cx, cy, w, h
            const float img_h = sizes[2 * b + 0];
            const float img_w = sizes[2 * b + 1];
            float4 ob;
            ob.x = (bx.x - 0.5f * bx.z) * img_w;
            ob.y = (bx.y - 0.5f * bx.w) * img_h;
            ob.z = (bx.x + 0.5f * bx.z) * img_w;
            ob.w = (bx.y + 0.5f * bx.w) * img_h;
            ((float4*)out_boxes)[o] = ob;
        } else {
            out_scores[o] = 0.0f;
            out_labels[o] = -1.0f;
            ((float4*)out_boxes)[o] = make_float4(0.0f, 0.0f, 0.0f, 0.0f);
        }
    }
}

extern "C" void kernel_launch(void* const* d_in, const int* in_sizes, int n_in,
                              void* d_out, int out_size, void* d_ws, size_t ws_size,
                              hipStream_t stream) {
    const float* logits = (const float*)d_in[0];   // [256,1000,80]
    const float* boxes  = (const float*)d_in[1];   // [256,1000,4]
    const float* sizes  = (const float*)d_in[2];   // [256,2]
    float* out = (float*)d_out;                    // 460800 floats

    rtdetr_post_kernel<<<BATCH, THREADS, 0, stream>>>(logits, boxes, sizes, out);
}

// Round 3
// 163.392 us; speedup vs baseline: 1.0154x; 1.0154x over previous
//
#include <hip/hip_runtime.h>
#include <math.h>

#define BATCH   256
#define NQ      1000
#define NC      80
#define NDET    300
#define THREADS 1024
#define TQ      250            // queries staged per pass
#define NPASS   4              // 4 * 250 = 1000
#define RSTRIDE 84             // padded LDS row stride in floats (16B-aligned: 84*4=336)
#define SCORE_TH 0.05f

__global__ __launch_bounds__(THREADS) void rtdetr_post_kernel(
    const float* __restrict__ logits,   // [B, Q, C]
    const float* __restrict__ boxes,    // [B, Q, 4]
    const float* __restrict__ sizes,    // [B, 2] (h, w)
    float* __restrict__ out)            // scores[B*K] | labels[B*K] | boxes[B*K*4]
{
    __shared__ __align__(16) float s_tile[TQ * RSTRIDE];   // 84.0 KB
    __shared__ __align__(16) unsigned int s_key[NQ];       // sigmoid bits, or 0 if masked
    __shared__ int s_lab[NQ];

    const int b = blockIdx.x;
    const int t = threadIdx.x;

    const float* blog = logits + (size_t)b * NQ * NC;

    for (int p = 0; p < NPASS; ++p) {
        // ---- stage: 250 queries * 80 floats = 5000 float4, fully coalesced ----
        const float4* g = (const float4*)(blog + (size_t)p * TQ * NC);
        #pragma unroll
        for (int k = 0; k < 5; ++k) {
            int j = t + k * THREADS;           // float4 index within the tile
            if (j < TQ * NC / 4) {
                float4 v = g[j];
                int q  = j / 20;               // 20 float4 per query row
                int c4 = j % 20;
                *(float4*)&s_tile[q * RSTRIDE + c4 * 4] = v;
            }
        }
        __syncthreads();

        // ---- reduce: 4 threads per query, 20 floats each ----
        const int ql = t >> 2;                 // query within tile
        const int r  = t & 3;                  // sub-slice
        float bv = -1e30f;
        int   bc = 0;
        if (ql < TQ) {
            const float* row = &s_tile[ql * RSTRIDE + r * 20];
            #pragma unroll
            for (int i = 0; i < 5; ++i) {
                float4 v = *(const float4*)&row[4 * i];
                int c = r * 20 + 4 * i;
                // strict > keeps FIRST (lowest) class among equal values
                if (v.x > bv) { bv = v.x; bc = c + 0; }
                if (v.y > bv) { bv = v.y; bc = c + 1; }
                if (v.z > bv) { bv = v.z; bc = c + 2; }
                if (v.w > bv) { bv = v.w; bc = c + 3; }
            }
        }
        // combine the 4 partials (lanes 4q..4q+3 of one wave); ties -> lower class
        #pragma unroll
        for (int d = 1; d <= 2; d <<= 1) {
            float ov = __shfl_xor(bv, d);
            int   oc = __shfl_xor(bc, d);
            if (ov > bv || (ov == bv && oc < bc)) { bv = ov; bc = oc; }
        }
        if (ql < TQ && r == 0) {
            // one sigmoid per query; fp32-identical to max(sigmoid(all)) (monotone)
            float sc = 1.0f / (1.0f + expf(-bv));
            int q = p * TQ + ql;
            s_key[q] = (sc > SCORE_TH) ? __float_as_uint(sc) : 0u;  // bits monotone for sc>0
            s_lab[q] = bc;
        }
        __syncthreads();   // protects s_tile reuse; after last pass, publishes s_key
    }

    // ---- phase 2: exact stable descending rank over u32 keys ----
    // key order = score desc; ties (equal fp32 score, and all masked entries
    // which share key 0) broken by index asc via the loop counter.
    if (t < NQ) {
        const unsigned int su = s_key[t];
        int rank = 0;
        const uint4* k4 = (const uint4*)s_key;
        for (int j4 = 0; j4 < NQ / 4; ++j4) {
            uint4 kv = k4[j4];                 // broadcast read, conflict-free
            int j = 4 * j4;
            rank += (kv.x > su) || (kv.x == su && (j + 0) < t);
            rank += (kv.y > su) || (kv.y == su && (j + 1) < t);
            rank += (kv.z > su) || (kv.z == su && (j + 2) < t);
            rank += (kv.w > su) || (kv.w == su && (j + 3) < t);
        }

        if (rank < NDET) {                     // ranks are a bijection -> exactly 300 writers
            float* out_scores = out;
            float* out_labels = out + (size_t)BATCH * NDET;
            float* out_boxes  = out + (size_t)2 * BATCH * NDET;
            const int o = b * NDET + rank;

            if (su != 0u) {                    // valid (score > threshold)
                out_scores[o] = __uint_as_float(su);
                out_labels[o] = (float)s_lab[t];
                float4 bx = ((const float4*)boxes)[b * NQ + t];   // cx, cy, w, h
                const float img_h = sizes[2 * b + 0];
                const float img_w = sizes[2 * b + 1];
                float4 ob;
                ob.x = (bx.x - 0.5f * bx.z) * img_w;
                ob.y = (bx.y - 0.5f * bx.w) * img_h;
                ob.z = (bx.x + 0.5f * bx.z) * img_w;
                ob.w = (bx.y + 0.5f * bx.w) * img_h;
                ((float4*)out_boxes)[o] = ob;
            } else {
                out_scores[o] = 0.0f;
                out_labels[o] = -1.0f;
                ((float4*)out_boxes)[o] = make_float4(0.0f, 0.0f, 0.0f, 0.0f);
            }
        }
    }
}

extern "C" void kernel_launch(void* const* d_in, const int* in_sizes, int n_in,
                              void* d_out, int out_size, void* d_ws, size_t ws_size,
                              hipStream_t stream) {
    const float* logits = (const float*)d_in[0];   // [256,1000,80]
    const float* boxes  = (const float*)d_in[1];   // [256,1000,4]
    const float* sizes  = (const float*)d_in[2];   // [256,2]
    float* out = (float*)d_out;                    // 460800 floats

    rtdetr_post_kernel<<<BATCH, THREADS, 0, stream>>>(logits, boxes, sizes, out);
}